// Round 17
// baseline (54.032 us; speedup 1.0000x reference)
//
#include <hip/hip_runtime.h>

// NEmbedding: out[b,f,e] = relu( x*P[f,e] + R[f,e] + c * W[f,k,e] ),
// c = (hi_k - x)/(hi_k - lo_k),  P = sum_n g_n W_n,  R = bias - sum_n lo_n g_n W_n,
// k = largest n with bins[f,n] <= x (0 if none); hi of last bin = -1.0.
//
// R1-R13: batching/fusion/slicing (56.4); dead: store flavor, barriers,
// W-gather, latency, occupancy, DS-op count, write contiguity.
// R14: zero global loads in main loop (no vmcnt store-gating) -> 52.0 (match).
// R15: search hoist + k-in-c-mantissa -> 51.7 (marginal; steady loop is fine).
// R16: prologue attack. NRPB 256 -> 512: halves block count (1024->512),
//      total W staging (64->32 MB), and per-CU prologue serialization (4->2).
//      Clean re-test of R8 persistence with both confounds (in-loop x loads,
//      nt-x) removed by the R14/R15 structure. P/R reduction split into two
//      independent 32-n chains (ILP 2). Grid 512 = 2 blocks/CU (R12 proved
//      2 vs 4 equivalent).
// R17: resubmit of R16 verbatim — container infra failure, no bench signal.

#define FDIM 64
#define NB   64
#define EDIM 32
#define FSL  8      // features per slice
#define NRPB 512    // rows per block
#define ITERS (NRPB / 32)   // 16
#define SWSTR 34    // bf16 per n-row = 17 dwords (odd -> bank spread)

typedef __attribute__((ext_vector_type(4))) float f32x4;

static __device__ __forceinline__ unsigned bf16rne(float f) {
    unsigned u = __float_as_uint(f);
    return (u + 0x7FFFu + ((u >> 16) & 1u)) >> 16;
}

__global__ __launch_bounds__(256) void nemb_fused(
    const float* __restrict__ x, const float* __restrict__ bins,
    const float* __restrict__ W, const float* __restrict__ bias,
    float* __restrict__ out)
{
    __shared__ unsigned short sW16[FSL * NB * SWSTR];  // 34.0 KB bf16
    __shared__ float sBins[FSL * 65];                  // 65th = -1.0 sentinel
    __shared__ float sP[FSL * EDIM];
    __shared__ float sR[FSL * EDIM];

    const int t     = threadIdx.x;
    const int slice = blockIdx.x & 7;         // XCD-affine under %8 dispatch
    const int chunk = blockIdx.x >> 3;
    const int f0    = slice * FSL;

    const int w  = t >> 6;
    const int l  = t & 63;
    const int rs = l >> 3;                    // search: row-in-8
    const int fs = l & 7;                     // search: f-in-slice
    const int ft = l >> 3;                    // store: f-in-slice
    const int e0 = (l & 7) * 4;               // store: e-quad

    const long r00 = (long)chunk * NRPB;

    // ---- stage sBins FIRST (searches depend only on it) ----
    if (t < 128) {
        f32x4 v = reinterpret_cast<const f32x4*>(bins + (size_t)f0 * NB)[t];
        int gi = t * 4;
        int fl = gi >> 6, n = gi & 63;
        float* d = &sBins[fl * 65 + n];
        d[0] = v.x; d[1] = v.y; d[2] = v.z; d[3] = v.w;
    }
    if (t < FSL) sBins[t * 65 + 64] = -1.0f;
    __syncthreads();                          // barrier 1: sBins ready

    // ---- issue xpre (consumed by searches) then staging half A ----
    float xpre[ITERS];
    #pragma unroll
    for (int it = 0; it < ITERS; ++it)
        xpre[it] = x[(r00 + it * 32 + w * 8 + rs) * FDIM + f0 + fs];
    float bias_v = bias[(f0 + (t >> 5)) * EDIM + (t & 31)];

    const float* Wg = W + (size_t)f0 * NB * EDIM;
    unsigned* sWd = reinterpret_cast<unsigned*>(sW16);

    f32x4 vstg[8];
    #pragma unroll
    for (int i = 0; i < 8; ++i)               // half A: fl 0..3
        vstg[i] = reinterpret_cast<const f32x4*>(Wg)[i * 256 + t];

    // ---- searches (pure sBins/VALU) run while half-A loads are in flight ----
    const float* bl = &sBins[fs * 65];
    unsigned pk[ITERS];
    #pragma unroll
    for (int it = 0; it < ITERS; ++it) {
        float xv = xpre[it];
        int k = 0;
        k += (bl[ 8] <= xv) ? 8 : 0;
        k += (bl[16] <= xv) ? 8 : 0;
        k += (bl[24] <= xv) ? 8 : 0;
        k += (bl[32] <= xv) ? 8 : 0;
        k += (bl[40] <= xv) ? 8 : 0;
        k += (bl[48] <= xv) ? 8 : 0;
        k += (bl[56] <= xv) ? 8 : 0;
        const float* b2 = bl + k;
        int inner = 0;
        inner += (b2[1] <= xv) ? 1 : 0;
        inner += (b2[2] <= xv) ? 1 : 0;
        inner += (b2[3] <= xv) ? 1 : 0;
        inner += (b2[4] <= xv) ? 1 : 0;
        inner += (b2[5] <= xv) ? 1 : 0;
        inner += (b2[6] <= xv) ? 1 : 0;
        inner += (b2[7] <= xv) ? 1 : 0;
        k += inner;
        float lo = bl[k];
        float hi = bl[k + 1];                 // k=63 -> sentinel -1.0
        float cv = (hi - xv) * __builtin_amdgcn_rcpf(hi - lo);
        pk[it] = (__float_as_uint(cv) & ~63u) | (unsigned)k;  // k in mantissa lo bits
    }

    // ---- write half A, issue+write half B ----
    #pragma unroll
    for (int i = 0; i < 8; ++i) {
        int gi = (i * 256 + t) * 4;
        int fl = gi >> 11, n = (gi >> 5) & 63, ee = gi & 31;
        unsigned u0 = bf16rne(vstg[i].x) | (bf16rne(vstg[i].y) << 16);
        unsigned u1 = bf16rne(vstg[i].z) | (bf16rne(vstg[i].w) << 16);
        int d0 = 17 * (fl * 64 + n) + (ee >> 1);
        sWd[d0] = u0; sWd[d0 + 1] = u1;
    }
    #pragma unroll
    for (int i = 8; i < 16; ++i)              // half B: fl 4..7
        vstg[i - 8] = reinterpret_cast<const f32x4*>(Wg)[i * 256 + t];
    #pragma unroll
    for (int i = 8; i < 16; ++i) {
        int gi = (i * 256 + t) * 4;
        int fl = gi >> 11, n = (gi >> 5) & 63, ee = gi & 31;
        unsigned u0 = bf16rne(vstg[i - 8].x) | (bf16rne(vstg[i - 8].y) << 16);
        unsigned u1 = bf16rne(vstg[i - 8].z) | (bf16rne(vstg[i - 8].w) << 16);
        int d0 = 17 * (fl * 64 + n) + (ee >> 1);
        sWd[d0] = u0; sWd[d0 + 1] = u1;
    }
    __syncthreads();                          // barrier 2: sW ready

    // ---- per-slice P/R from sBins (rcp) + bf16 sW; two ILP-2 chains ----
    {
        const int fl = t >> 5;
        const int e  = t & 31;
        float p0 = 0.0f, q0 = 0.0f, p1 = 0.0f, q1 = 0.0f;
        #pragma unroll
        for (int n = 0; n < NB / 2; ++n) {
            float loA = sBins[fl * 65 + n];
            float hiA = sBins[fl * 65 + n + 1];
            float gA  = __builtin_amdgcn_rcpf(hiA - loA);
            float wA  = __uint_as_float((unsigned)sW16[(fl * 64 + n) * SWSTR + e] << 16);
            p0 = fmaf(gA, wA, p0);
            q0 = fmaf(loA * gA, wA, q0);
            int m = n + NB / 2;
            float loB = sBins[fl * 65 + m];
            float hiB = sBins[fl * 65 + m + 1];
            float gB  = __builtin_amdgcn_rcpf(hiB - loB);
            float wB  = __uint_as_float((unsigned)sW16[(fl * 64 + m) * SWSTR + e] << 16);
            p1 = fmaf(gB, wB, p1);
            q1 = fmaf(loB * gB, wB, q1);
        }
        sP[fl * EDIM + e] = p0 + p1;
        sR[fl * EDIM + e] = bias_v - (q0 + q1);
    }
    __syncthreads();                          // barrier 3: sP/sR ready

    const f32x4 Pv = *reinterpret_cast<const f32x4*>(&sP[ft * EDIM + e0]);
    const f32x4 Rv = *reinterpret_cast<const f32x4*>(&sR[ft * EDIM + e0]);
    const int bp_base = (l >> 3) * 4;         // bpermute byte addr component

    // ---- main loop: ZERO global loads, ZERO searches — just emit ----
    #pragma unroll
    for (int it = 0; it < ITERS; ++it) {
        const long rb = r00 + it * 32 + w * 8;
        const float    xv  = xpre[it];
        const unsigned pkv = pk[it];

        #pragma unroll
        for (int r = 0; r < 8; ++r) {
            const int a = bp_base + r * 32;   // src_lane*4
            float xr = __uint_as_float((unsigned)
                __builtin_amdgcn_ds_bpermute(a, (int)__float_as_uint(xv)));
            unsigned pr = (unsigned)__builtin_amdgcn_ds_bpermute(a, (int)pkv);
            int   kr = (int)(pr & 63u);
            float cr = __uint_as_float(pr & ~63u);

            int d0 = 17 * (ft * 64 + kr) + ((l & 7) << 1);
            unsigned u0 = sWd[d0];
            unsigned u1 = sWd[d0 + 1];
            f32x4 Wv;
            Wv.x = __uint_as_float(u0 << 16);
            Wv.y = __uint_as_float(u0 & 0xFFFF0000u);
            Wv.z = __uint_as_float(u1 << 16);
            Wv.w = __uint_as_float(u1 & 0xFFFF0000u);

            f32x4 o;
            o.x = fmaxf(fmaf(cr, Wv.x, fmaf(xr, Pv.x, Rv.x)), 0.0f);
            o.y = fmaxf(fmaf(cr, Wv.y, fmaf(xr, Pv.y, Rv.y)), 0.0f);
            o.z = fmaxf(fmaf(cr, Wv.z, fmaf(xr, Pv.z, Rv.z)), 0.0f);
            o.w = fmaxf(fmaf(cr, Wv.w, fmaf(xr, Pv.w, Rv.w)), 0.0f);
            *reinterpret_cast<f32x4*>(
                out + (rb + r) * (FDIM * EDIM) + (f0 + ft) * EDIM + e0) = o;
        }
    }
}

extern "C" void kernel_launch(void* const* d_in, const int* in_sizes, int n_in,
                              void* d_out, int out_size, void* d_ws, size_t ws_size,
                              hipStream_t stream) {
    const float* x    = (const float*)d_in[0];   // (B, F)
    const float* bins = (const float*)d_in[1];   // (F, NB) sorted rows
    const float* W    = (const float*)d_in[2];   // (F, NB, E)
    const float* bias = (const float*)d_in[3];   // (F, E)
    float* out = (float*)d_out;

    const int B = in_sizes[0] / FDIM;            // 32768
    const int nchunks = B / NRPB;                // 64

    nemb_fused<<<nchunks * 8, 256, 0, stream>>>(x, bins, W, bias, out);
}

// Round 21
// 52.120 us; speedup vs baseline: 1.0367x; 1.0367x over previous
//
#include <hip/hip_runtime.h>

// NEmbedding: out[b,f,e] = relu( x*P[f,e] + R[f,e] + c * W[f,k,e] ),
// c = (hi_k - x)/(hi_k - lo_k),  P = sum_n g_n W_n,  R = bias - sum_n lo_n g_n W_n,
// k = largest n with bins[f,n] <= x (0 if none); hi of last bin = -1.0.
//
// R1-R13: batching, fusion, slicing (56.4); dead theories: store flavor,
// barriers, W-gather, latency, occupancy, DS-op count, write contiguity.
// R14: zero global loads in main loop -> 52.0 (vmcnt store-gating, confirmed).
// R15: search hoist + k-in-c-mantissa -> 51.7 (BEST, verified).
// R17: NRPB=512 @256thr regressed (54.0). R18-R20: 512-thread prologue test
//      never ran — 3 consecutive container infra failures (pre-push).
// R21: re-anchor on R15 verbatim (proven best). Prologue axis abandoned:
//      bounded upside (~1.5us), proven regression risk (R17), and repeated
//      infra loss. Expect ~51.7; declare roofline on clean pass.

#define FDIM 64
#define NB   64
#define EDIM 32
#define FSL  8      // features per slice
#define NRPB 256    // rows per block
#define ITERS (NRPB / 32)
#define SWSTR 34    // bf16 per n-row = 17 dwords (odd -> bank spread)

typedef __attribute__((ext_vector_type(4))) float f32x4;

static __device__ __forceinline__ unsigned bf16rne(float f) {
    unsigned u = __float_as_uint(f);
    return (u + 0x7FFFu + ((u >> 16) & 1u)) >> 16;
}

__global__ __launch_bounds__(256) void nemb_fused(
    const float* __restrict__ x, const float* __restrict__ bins,
    const float* __restrict__ W, const float* __restrict__ bias,
    float* __restrict__ out)
{
    __shared__ unsigned short sW16[FSL * NB * SWSTR];  // 34.0 KB bf16
    __shared__ float sBins[FSL * 65];                  // 65th = -1.0 sentinel
    __shared__ float sP[FSL * EDIM];
    __shared__ float sR[FSL * EDIM];

    const int t     = threadIdx.x;
    const int slice = blockIdx.x & 7;         // XCD-affine under %8 dispatch
    const int chunk = blockIdx.x >> 3;
    const int f0    = slice * FSL;

    const int w  = t >> 6;
    const int l  = t & 63;
    const int rs = l >> 3;                    // search: row-in-8
    const int fs = l & 7;                     // search: f-in-slice
    const int ft = l >> 3;                    // store: f-in-slice
    const int e0 = (l & 7) * 4;               // store: e-quad

    const long r00 = (long)chunk * NRPB;

    // ---- stage sBins FIRST (searches depend only on it) ----
    if (t < 128) {
        f32x4 v = reinterpret_cast<const f32x4*>(bins + (size_t)f0 * NB)[t];
        int gi = t * 4;
        int fl = gi >> 6, n = gi & 63;
        float* d = &sBins[fl * 65 + n];
        d[0] = v.x; d[1] = v.y; d[2] = v.z; d[3] = v.w;
    }
    if (t < FSL) sBins[t * 65 + 64] = -1.0f;
    __syncthreads();                          // barrier 1: sBins ready

    // ---- issue xpre (consumed by searches) then staging half A ----
    float xpre[ITERS];
    #pragma unroll
    for (int it = 0; it < ITERS; ++it)
        xpre[it] = x[(r00 + it * 32 + w * 8 + rs) * FDIM + f0 + fs];
    float bias_v = bias[(f0 + (t >> 5)) * EDIM + (t & 31)];

    const float* Wg = W + (size_t)f0 * NB * EDIM;
    unsigned* sWd = reinterpret_cast<unsigned*>(sW16);

    f32x4 vstg[8];
    #pragma unroll
    for (int i = 0; i < 8; ++i)               // half A: fl 0..3
        vstg[i] = reinterpret_cast<const f32x4*>(Wg)[i * 256 + t];

    // ---- searches (pure sBins/VALU) run while half-A loads are in flight ----
    const float* bl = &sBins[fs * 65];
    unsigned pk[ITERS];
    #pragma unroll
    for (int it = 0; it < ITERS; ++it) {
        float xv = xpre[it];
        int k = 0;
        k += (bl[ 8] <= xv) ? 8 : 0;
        k += (bl[16] <= xv) ? 8 : 0;
        k += (bl[24] <= xv) ? 8 : 0;
        k += (bl[32] <= xv) ? 8 : 0;
        k += (bl[40] <= xv) ? 8 : 0;
        k += (bl[48] <= xv) ? 8 : 0;
        k += (bl[56] <= xv) ? 8 : 0;
        const float* b2 = bl + k;
        int inner = 0;
        inner += (b2[1] <= xv) ? 1 : 0;
        inner += (b2[2] <= xv) ? 1 : 0;
        inner += (b2[3] <= xv) ? 1 : 0;
        inner += (b2[4] <= xv) ? 1 : 0;
        inner += (b2[5] <= xv) ? 1 : 0;
        inner += (b2[6] <= xv) ? 1 : 0;
        inner += (b2[7] <= xv) ? 1 : 0;
        k += inner;
        float lo = bl[k];
        float hi = bl[k + 1];                 // k=63 -> sentinel -1.0
        float cv = (hi - xv) * __builtin_amdgcn_rcpf(hi - lo);
        pk[it] = (__float_as_uint(cv) & ~63u) | (unsigned)k;  // k in mantissa lo bits
    }

    // ---- write half A, issue+write half B ----
    #pragma unroll
    for (int i = 0; i < 8; ++i) {
        int gi = (i * 256 + t) * 4;
        int fl = gi >> 11, n = (gi >> 5) & 63, ee = gi & 31;
        unsigned u0 = bf16rne(vstg[i].x) | (bf16rne(vstg[i].y) << 16);
        unsigned u1 = bf16rne(vstg[i].z) | (bf16rne(vstg[i].w) << 16);
        int d0 = 17 * (fl * 64 + n) + (ee >> 1);
        sWd[d0] = u0; sWd[d0 + 1] = u1;
    }
    #pragma unroll
    for (int i = 8; i < 16; ++i)              // half B: fl 4..7
        vstg[i - 8] = reinterpret_cast<const f32x4*>(Wg)[i * 256 + t];
    #pragma unroll
    for (int i = 8; i < 16; ++i) {
        int gi = (i * 256 + t) * 4;
        int fl = gi >> 11, n = (gi >> 5) & 63, ee = gi & 31;
        unsigned u0 = bf16rne(vstg[i - 8].x) | (bf16rne(vstg[i - 8].y) << 16);
        unsigned u1 = bf16rne(vstg[i - 8].z) | (bf16rne(vstg[i - 8].w) << 16);
        int d0 = 17 * (fl * 64 + n) + (ee >> 1);
        sWd[d0] = u0; sWd[d0 + 1] = u1;
    }
    __syncthreads();                          // barrier 2: sW ready

    // ---- per-slice P/R from sBins (rcp) + bf16 sW ----
    {
        const int fl = t >> 5;
        const int e  = t & 31;
        float p = 0.0f, q = 0.0f;
        #pragma unroll
        for (int n = 0; n < NB; ++n) {
            float lo = sBins[fl * 65 + n];
            float hi = sBins[fl * 65 + n + 1];
            float gv = __builtin_amdgcn_rcpf(hi - lo);
            float wv = __uint_as_float((unsigned)sW16[(fl * 64 + n) * SWSTR + e] << 16);
            p = fmaf(gv, wv, p);
            q = fmaf(lo * gv, wv, q);
        }
        sP[fl * EDIM + e] = p;
        sR[fl * EDIM + e] = bias_v - q;
    }
    __syncthreads();                          // barrier 3: sP/sR ready

    const f32x4 Pv = *reinterpret_cast<const f32x4*>(&sP[ft * EDIM + e0]);
    const f32x4 Rv = *reinterpret_cast<const f32x4*>(&sR[ft * EDIM + e0]);
    const int bp_base = (l >> 3) * 4;         // bpermute byte addr component

    // ---- main loop: ZERO global loads, ZERO searches — just emit ----
    #pragma unroll
    for (int it = 0; it < ITERS; ++it) {
        const long rb = r00 + it * 32 + w * 8;
        const float    xv  = xpre[it];
        const unsigned pkv = pk[it];

        #pragma unroll
        for (int r = 0; r < 8; ++r) {
            const int a = bp_base + r * 32;   // src_lane*4
            float xr = __uint_as_float((unsigned)
                __builtin_amdgcn_ds_bpermute(a, (int)__float_as_uint(xv)));
            unsigned pr = (unsigned)__builtin_amdgcn_ds_bpermute(a, (int)pkv);
            int   kr = (int)(pr & 63u);
            float cr = __uint_as_float(pr & ~63u);

            int d0 = 17 * (ft * 64 + kr) + ((l & 7) << 1);
            unsigned u0 = sWd[d0];
            unsigned u1 = sWd[d0 + 1];
            f32x4 Wv;
            Wv.x = __uint_as_float(u0 << 16);
            Wv.y = __uint_as_float(u0 & 0xFFFF0000u);
            Wv.z = __uint_as_float(u1 << 16);
            Wv.w = __uint_as_float(u1 & 0xFFFF0000u);

            f32x4 o;
            o.x = fmaxf(fmaf(cr, Wv.x, fmaf(xr, Pv.x, Rv.x)), 0.0f);
            o.y = fmaxf(fmaf(cr, Wv.y, fmaf(xr, Pv.y, Rv.y)), 0.0f);
            o.z = fmaxf(fmaf(cr, Wv.z, fmaf(xr, Pv.z, Rv.z)), 0.0f);
            o.w = fmaxf(fmaf(cr, Wv.w, fmaf(xr, Pv.w, Rv.w)), 0.0f);
            *reinterpret_cast<f32x4*>(
                out + (rb + r) * (FDIM * EDIM) + (f0 + ft) * EDIM + e0) = o;
        }
    }
}

extern "C" void kernel_launch(void* const* d_in, const int* in_sizes, int n_in,
                              void* d_out, int out_size, void* d_ws, size_t ws_size,
                              hipStream_t stream) {
    const float* x    = (const float*)d_in[0];   // (B, F)
    const float* bins = (const float*)d_in[1];   // (F, NB) sorted rows
    const float* W    = (const float*)d_in[2];   // (F, NB, E)
    const float* bias = (const float*)d_in[3];   // (F, E)
    float* out = (float*)d_out;

    const int B = in_sizes[0] / FDIM;            // 32768
    const int nchunks = B / NRPB;                // 128

    nemb_fused<<<nchunks * 8, 256, 0, stream>>>(x, bins, W, bias, out);
}